// Round 7
// baseline (305.600 us; speedup 1.0000x reference)
//
#include <hip/hip_runtime.h>

// LinearAttentionBlock bf16 MFMA. Attention reassociated: Q@(K'V).
// FFN GEMMs: 256x256/BK=64 4-phase pipeline with ONE-PHASE READ-AHEAD:
//   every MFMA quadrant consumes ds_reads issued >=1 phase earlier
//   (ph_p reads A-quad for Q_{p+1}; ph3 reads next tile's B + m0-1).
//   Stage 1 half-tile per phase; WAITV(6) before ph2's trailing barrier
//   (so ph3 may read tile t+1); LGKM0 before ph2/ph3 trailing barriers
//   protects LDS slot reuse. B regs ping-pong via 2x-unrolled tile loop.
// Epilogues: n-innermost bf16 stores (fixes 4.5x write amplification).
// FFN2: split-K=2 (256 blocks) + fused reduce. Small GEMMs: m97 128x128.

#define MROWS 8192
#define DMODEL 1024
#define DK 128
#define DFF 4096

typedef __attribute__((ext_vector_type(8))) __bf16 bf16x8;
typedef __attribute__((ext_vector_type(4))) float f32x4;

#define BAR()    asm volatile("s_barrier" ::: "memory")
#define WAITV(n) asm volatile("s_waitcnt vmcnt(" #n ")" ::: "memory")
#define LGKM0()  asm volatile("s_waitcnt lgkmcnt(0)" ::: "memory")
#define GLOAD(src, dst) __builtin_amdgcn_global_load_lds( \
    (const __attribute__((address_space(1))) void*)(src), \
    (__attribute__((address_space(3))) void*)(dst), 16, 0, 0)

__global__ __launch_bounds__(256) void cast_f32_bf16(
    const float* __restrict__ src, __bf16* __restrict__ dst, int n8)
{
    for (int i = blockIdx.x * blockDim.x + threadIdx.x; i < n8;
         i += gridDim.x * blockDim.x) {
        const float4 a = reinterpret_cast<const float4*>(src)[2 * i];
        const float4 b = reinterpret_cast<const float4*>(src)[2 * i + 1];
        bf16x8 o;
        o[0] = (__bf16)a.x; o[1] = (__bf16)a.y; o[2] = (__bf16)a.z; o[3] = (__bf16)a.w;
        o[4] = (__bf16)b.x; o[5] = (__bf16)b.y; o[6] = (__bf16)b.z; o[7] = (__bf16)b.w;
        reinterpret_cast<bf16x8*>(dst)[i] = o;
    }
}

__global__ void pack_bias3(const float* __restrict__ a, const float* __restrict__ b,
                           const float* __restrict__ c, float* __restrict__ o)
{
    const int t = threadIdx.x;
    o[t] = a[t]; o[128 + t] = b[t]; o[256 + t] = c[t];
}

// y = x2 + P0 + P1 + b2   (all [8192][1024]; P bf16, rest fp32; in-place on y)
__global__ __launch_bounds__(256) void ffn2_reduce(
    float* __restrict__ y, const __bf16* __restrict__ P0,
    const __bf16* __restrict__ P1, const float* __restrict__ b2, int n8)
{
    for (int i = blockIdx.x * blockDim.x + threadIdx.x; i < n8;
         i += gridDim.x * blockDim.x) {
        const int col0 = (i << 3) & (DMODEL - 1);
        const float4 ba = *reinterpret_cast<const float4*>(&b2[col0]);
        const float4 bb = *reinterpret_cast<const float4*>(&b2[col0 + 4]);
        float4 o0 = reinterpret_cast<const float4*>(y)[2 * i];
        float4 o1 = reinterpret_cast<const float4*>(y)[2 * i + 1];
        const bf16x8 p0 = reinterpret_cast<const bf16x8*>(P0)[i];
        const bf16x8 p1 = reinterpret_cast<const bf16x8*>(P1)[i];
        o0.x += (float)p0[0] + (float)p1[0] + ba.x;
        o0.y += (float)p0[1] + (float)p1[1] + ba.y;
        o0.z += (float)p0[2] + (float)p1[2] + ba.z;
        o0.w += (float)p0[3] + (float)p1[3] + ba.w;
        o1.x += (float)p0[4] + (float)p1[4] + bb.x;
        o1.y += (float)p0[5] + (float)p1[5] + bb.y;
        o1.z += (float)p0[6] + (float)p1[6] + bb.z;
        o1.w += (float)p0[7] + (float)p1[7] + bb.w;
        reinterpret_cast<float4*>(y)[2 * i]     = o0;
        reinterpret_cast<float4*>(y)[2 * i + 1] = o1;
    }
}

// ---------------------------------------------------------------------------
// 128x128 m97-style GEMM. DUAL adds a bf16 secondary output.
// ---------------------------------------------------------------------------
template<bool RELU, bool RESID, bool BIAS, bool OUTBF, bool DUAL>
__global__ __launch_bounds__(256) void gemm128(
    const __bf16* __restrict__ A, int lda,
    const __bf16* __restrict__ W,
    const float* __restrict__ bias,
    const float* __restrict__ resid,
    void* __restrict__ Cout, __bf16* __restrict__ Cbf, int ldc, int K)
{
    constexpr int BK = 32;
    __shared__ __bf16 As[128 * BK];
    __shared__ __bf16 Bs[128 * BK];

    const int tid  = threadIdx.x;
    const int lane = tid & 63;
    const int w    = tid >> 6;
    const int wm   = w >> 1;
    const int wn   = w & 1;
    const int fr   = lane & 15;
    const int fq   = lane >> 4;

    const long row0 = (long)blockIdx.y * 128;
    const long col0 = (long)blockIdx.x * 128;

    const int sr = (w << 4) + (lane >> 2);
    const int sc = (lane & 3) << 3;

    const __bf16* gA0 = A + (row0 + sr) * (long)lda + sc;
    const __bf16* gA1 = A + (row0 + 64 + sr) * (long)lda + sc;
    const __bf16* gW0 = W + (col0 + sr) * (long)K + sc;
    const __bf16* gW1 = W + (col0 + 64 + sr) * (long)K + sc;

    __bf16* lA0 = &As[(w << 4) * BK];
    __bf16* lA1 = &As[((w << 4) + 64) * BK];
    __bf16* lB0 = &Bs[(w << 4) * BK];
    __bf16* lB1 = &Bs[((w << 4) + 64) * BK];

    f32x4 acc[4][4] = {};

    for (int k0 = 0; k0 < K; k0 += BK) {
        GLOAD(gA0 + k0, lA0);
        GLOAD(gA1 + k0, lA1);
        GLOAD(gW0 + k0, lB0);
        GLOAD(gW1 + k0, lB1);
        __syncthreads();

        bf16x8 af[4], bfr[4];
        #pragma unroll
        for (int m = 0; m < 4; m++)
            af[m] = *reinterpret_cast<const bf16x8*>(
                &As[(wm * 64 + m * 16 + fr) * BK + fq * 8]);
        #pragma unroll
        for (int n = 0; n < 4; n++)
            bfr[n] = *reinterpret_cast<const bf16x8*>(
                &Bs[(wn * 64 + n * 16 + fr) * BK + fq * 8]);

        #pragma unroll
        for (int m = 0; m < 4; m++)
            #pragma unroll
            for (int n = 0; n < 4; n++)
                acc[m][n] = __builtin_amdgcn_mfma_f32_16x16x32_bf16(
                    af[m], bfr[n], acc[m][n], 0, 0, 0);
        __syncthreads();
    }

    // epilogue, n innermost (write-combine friendly)
    float bc[4];
    #pragma unroll
    for (int n = 0; n < 4; n++)
        bc[n] = BIAS ? bias[col0 + wn * 64 + n * 16 + fr] : 0.0f;
    #pragma unroll
    for (int m = 0; m < 4; m++) {
        #pragma unroll
        for (int j = 0; j < 4; j++) {
            const long r = row0 + wm * 64 + m * 16 + fq * 4 + j;
            #pragma unroll
            for (int n = 0; n < 4; n++) {
                const long c = col0 + wn * 64 + n * 16 + fr;
                float v = acc[m][n][j] + bc[n];
                if constexpr (RESID) v += resid[r * ldc + c];
                if constexpr (RELU)  v = fmaxf(v, 0.0f);
                if constexpr (OUTBF) ((__bf16*)Cout)[r * ldc + c] = (__bf16)v;
                else                 ((float*)Cout)[r * ldc + c] = v;
                if constexpr (DUAL)  Cbf[r * ldc + c] = (__bf16)v;
            }
        }
    }
}

// ---------------------------------------------------------------------------
// 256x256/BK=64 pipelined GEMM, 512 thr = 8 waves (2M x 4N), per-wave 128x64.
// LDS = 2 tile-slots x 4 half-slots x 16KB (j: 0=B0,1=B1,2=A0,3=A1).
// One-phase read-ahead (see header comment). Requires nt = klen/64 even, >=2.
// Split-K: shard sid = bid/nb; A,W offset by sid*klen; out at sid*sstride.
// ---------------------------------------------------------------------------
#define LD8(p) (*reinterpret_cast<const bf16x8*>(p))

#define READ_AQ(q, mb, pa)                         \
    q[0][0] = LD8((pa) + rb0 + (mb) * 2048);       \
    q[0][1] = LD8((pa) + rb1 + (mb) * 2048);       \
    q[1][0] = LD8((pa) + rb0 + ((mb) + 1) * 2048); \
    q[1][1] = LD8((pa) + rb1 + ((mb) + 1) * 2048);

#define READ_B(bset, pb)                           \
    _Pragma("unroll")                              \
    for (int n = 0; n < 4; n++) {                  \
        bset[n][0] = LD8((pb) + rb0 + n * 2048);   \
        bset[n][1] = LD8((pb) + rb1 + n * 2048);   \
    }

#define MFMA_Q(q, bset, mb)                                                   \
    _Pragma("unroll")                                                         \
    for (int i = 0; i < 2; i++)                                               \
        _Pragma("unroll")                                                     \
        for (int n = 0; n < 4; n++) {                                         \
            acc[(mb) + i][n] = __builtin_amdgcn_mfma_f32_16x16x32_bf16(       \
                q[i][0], bset[n][0], acc[(mb) + i][n], 0, 0, 0);              \
            acc[(mb) + i][n] = __builtin_amdgcn_mfma_f32_16x16x32_bf16(       \
                q[i][1], bset[n][1], acc[(mb) + i][n], 0, 0, 0);              \
        }

#define TILE(t, BCUR, BNXT)                                                   \
  {                                                                           \
    const char* pA  = ldsc + (((t) & 1) << 16) + ((2 + wm) << 14);            \
    const char* pAn = ldsc + ((((t) + 1) & 1) << 16) + ((2 + wm) << 14);      \
    const char* pBn = ldsc + ((((t) + 1) & 1) << 16) +                        \
                      ((wn >> 1) << 14) + ((wn & 1) << 13);                   \
    /* ph0: read A m2-3 (for Q1); stage t+2 B0; MFMA Q0 */                    \
    READ_AQ(qY, 2, pA); stage((t) + 2, 0);                                    \
    BAR();                                                                    \
    __builtin_amdgcn_s_setprio(1); MFMA_Q(qX, BCUR, 0);                       \
    __builtin_amdgcn_s_setprio(0);                                            \
    BAR();                                                                    \
    /* ph1: read A m4-5; stage t+2 B1; MFMA Q1 */                             \
    READ_AQ(qX, 4, pA); stage((t) + 2, 1);                                    \
    BAR();                                                                    \
    __builtin_amdgcn_s_setprio(1); MFMA_Q(qY, BCUR, 2);                       \
    __builtin_amdgcn_s_setprio(0);                                            \
    BAR();                                                                    \
    /* ph2: read A m6-7; stage t+2 A0; MFMA Q2; retire t+1's loads */         \
    READ_AQ(qY, 6, pA); stage((t) + 2, 2);                                    \
    BAR();                                                                    \
    __builtin_amdgcn_s_setprio(1); MFMA_Q(qX, BCUR, 4);                       \
    __builtin_amdgcn_s_setprio(0);                                            \
    if ((t) + 2 < nt)      { WAITV(6); }                                      \
    else if ((t) + 1 < nt) { WAITV(0); }                                      \
    LGKM0();                                                                  \
    BAR();                                                                    \
    /* ph3: read NEXT tile's B + A m0-1; stage t+2 A1; MFMA Q3 */             \
    if ((t) + 1 < nt) { READ_B(BNXT, pBn); READ_AQ(qX, 0, pAn); }             \
    stage((t) + 2, 3);                                                        \
    BAR();                                                                    \
    __builtin_amdgcn_s_setprio(1); MFMA_Q(qY, BCUR, 6);                       \
    __builtin_amdgcn_s_setprio(0);                                            \
    LGKM0();                                                                  \
    BAR();                                                                    \
  }

template<bool RELU, bool RESID, bool BIAS, bool OUTBF>
__global__ __launch_bounds__(512, 2) void gemm256p(
    const __bf16* __restrict__ A, int lda,
    const __bf16* __restrict__ W, int ldw,
    const float* __restrict__ bias,
    const float* __restrict__ resid,
    void* __restrict__ Cout, long sstride, int ldc,
    int klen, int nb, int nbx)
{
    __shared__ char lds[8][16384];

    const int bid = blockIdx.x;
    const int sid = bid / nb;
    const int ib  = bid % nb;
    const int chunk = nb >> 3;
    const int swz   = (ib & 7) * chunk + (ib >> 3);
    const int bx    = swz % nbx;
    const int by    = swz / nbx;

    const long row0 = (long)by * 256;
    const long col0 = (long)bx * 256;

    const __bf16* Ash = A + (long)sid * klen;
    const __bf16* Wsh = W + (long)sid * klen;

    const int tid  = threadIdx.x;
    const int lane = tid & 63;
    const int w    = tid >> 6;
    const int wm   = w >> 2;
    const int wn   = w & 3;
    const int fr   = lane & 15;
    const int fq   = lane >> 4;

    const int srow8 = lane >> 3;
    const int scole = ((lane & 7) ^ srow8) << 3;    // T2 pre-swizzled col
    const __bf16* gA = Ash + (row0 + w * 8 + srow8) * (long)lda + scole;
    const __bf16* gB = Wsh + (col0 + w * 8 + srow8) * (long)ldw + scole;

    char* ldsc = &lds[0][0];
    const int nt = klen >> 6;   // even, >= 2

    auto stage = [&](int u, int j) {
        if (u >= nt) return;
        char* dst = ldsc + (((u & 1) << 2 | j) << 14) + (w << 10);
        if (j < 2) {
            const __bf16* s = gB + ((long)j * 128) * (long)ldw + (long)u * 64;
            GLOAD(s, dst);
            GLOAD(s + 64 * (long)ldw, dst + 8192);
        } else {
            const __bf16* s = gA + ((long)(j - 2) * 128) * (long)lda + (long)u * 64;
            GLOAD(s, dst);
            GLOAD(s + 64 * (long)lda, dst + 8192);
        }
    };

    const int rb0 = fr * 128 + ((fq * 16) ^ ((fr & 7) << 4));
    const int rb1 = fr * 128 + ((64 + fq * 16) ^ ((fr & 7) << 4));

    f32x4 acc[8][4] = {};
    bf16x8 bE[4][2], bO[4][2], qX[2][2], qY[2][2];

    // prologue: stage tiles 0,1 fully; wait tile0; pre-read tile0 B + m0-1
    stage(0, 0); stage(0, 1); stage(0, 2); stage(0, 3);
    stage(1, 0); stage(1, 1); stage(1, 2); stage(1, 3);
    WAITV(8);
    BAR();
    {
        const char* pB0 = ldsc + ((wn >> 1) << 14) + ((wn & 1) << 13);
        const char* pA0 = ldsc + ((2 + wm) << 14);
        READ_B(bE, pB0);
        READ_AQ(qX, 0, pA0);
    }
    LGKM0();
    BAR();

    for (int tt = 0; tt < nt; tt += 2) {
        TILE(tt,     bE, bO)
        TILE(tt + 1, bO, bE)
    }

    // epilogue: C/D layout col = lane&15, row = (lane>>4)*4 + reg; n innermost
    __bf16* Cb = (__bf16*)Cout + (long)sid * sstride;
    float*  Cf = (float*)Cout;
    float bc[4];
    #pragma unroll
    for (int n = 0; n < 4; n++)
        bc[n] = BIAS ? bias[col0 + wn * 64 + n * 16 + fr] : 0.0f;
    #pragma unroll
    for (int m = 0; m < 8; m++) {
        #pragma unroll
        for (int j = 0; j < 4; j++) {
            const long r = row0 + wm * 128 + m * 16 + fq * 4 + j;
            #pragma unroll
            for (int n = 0; n < 4; n++) {
                const long c = col0 + wn * 64 + n * 16 + fr;
                float v = acc[m][n][j] + bc[n];
                if constexpr (RESID) v += resid[r * ldc + c];
                if constexpr (RELU)  v = fmaxf(v, 0.0f);
                if constexpr (OUTBF) Cb[r * ldc + c] = (__bf16)v;
                else                 Cf[r * ldc + c] = v;
            }
        }
    }
}

// ---------------------------------------------------------------------------
// K^T @ V partials + reduce
// ---------------------------------------------------------------------------
__global__ __launch_bounds__(256) void ktv_partial(
    const __bf16* __restrict__ Kp, const __bf16* __restrict__ Vp,
    int ld, float* __restrict__ part)
{
    __shared__ float ks[32][DK];
    __shared__ float vs[32][DK];
    const int tid = threadIdx.x;
    const int ti  = tid >> 4;
    const int tj  = tid & 15;
    float acc[8][8] = {};
    const long base = (long)blockIdx.x * 128;

    for (int n0 = 0; n0 < 128; n0 += 32) {
        for (int t = tid; t < 512; t += 256) {
            const int r  = t >> 4;
            const int cc = (t & 15) << 3;
            const bf16x8 k8 = *reinterpret_cast<const bf16x8*>(
                &Kp[(base + n0 + r) * (long)ld + cc]);
            const bf16x8 v8 = *reinterpret_cast<const bf16x8*>(
                &Vp[(base + n0 + r) * (long)ld + cc]);
            #pragma unroll
            for (int u = 0; u < 8; u++) {
                ks[r][cc + u] = (float)k8[u];
                vs[r][cc + u] = (float)v8[u];
            }
        }
        __syncthreads();
        for (int n = 0; n < 32; n++) {
            float kk[8], vv[8];
            #pragma unroll
            for (int i = 0; i < 8; i++) kk[i] = ks[n][(ti << 3) + i];
            #pragma unroll
            for (int j = 0; j < 8; j++) vv[j] = vs[n][(tj << 3) + j];
            #pragma unroll
            for (int i = 0; i < 8; i++)
                #pragma unroll
                for (int j = 0; j < 8; j++)
                    acc[i][j] = fmaf(kk[i], vv[j], acc[i][j]);
        }
        __syncthreads();
    }

    float* dst = &part[(long)blockIdx.x * (DK * DK)];
    #pragma unroll
    for (int i = 0; i < 8; i++) {
        const int ig = (ti << 3) + i;
        *reinterpret_cast<float4*>(&dst[ig * DK + (tj << 3)]) =
            make_float4(acc[i][0], acc[i][1], acc[i][2], acc[i][3]);
        *reinterpret_cast<float4*>(&dst[ig * DK + (tj << 3) + 4]) =
            make_float4(acc[i][4], acc[i][5], acc[i][6], acc[i][7]);
    }
}

__global__ __launch_bounds__(256) void ktv_reduce(
    const float* __restrict__ part, __bf16* __restrict__ ktvT)
{
    const int t = blockIdx.x * 256 + threadIdx.x;
    const int i = t >> 7;
    const int j = t & 127;
    float s = 0.0f;
    for (int b = 0; b < 64; b++) s += part[(long)b * (DK * DK) + t];
    ktvT[j * DK + i] = (__bf16)s;
}

// ---------------------------------------------------------------------------
extern "C" void kernel_launch(void* const* d_in, const int* in_sizes, int n_in,
                              void* d_out, int out_size, void* d_ws, size_t ws_size,
                              hipStream_t stream) {
    const float* x  = (const float*)d_in[0];
    const float* Wq = (const float*)d_in[1];
    const float* bq = (const float*)d_in[2];
    const float* Wk = (const float*)d_in[3];
    const float* bk = (const float*)d_in[4];
    const float* Wv = (const float*)d_in[5];
    const float* bv = (const float*)d_in[6];
    const float* Wp = (const float*)d_in[7];
    const float* bp = (const float*)d_in[8];
    const float* W1 = (const float*)d_in[9];
    const float* b1 = (const float*)d_in[10];
    const float* W2 = (const float*)d_in[11];
    const float* b2 = (const float*)d_in[12];
    float* out = (float*)d_out;

    char* ws = (char*)d_ws;
    const size_t MB = 1ull << 20;
    __bf16* xb    = (__bf16*)(ws);              // 16 MiB (dead after QKV)
    __bf16* P0    = (__bf16*)(ws);              // shard-0 partial
    __bf16* P1    = P0 + (long)MROWS * DMODEL;  // shard-1 partial (ws+16MiB)
    __bf16* x2b   = (__bf16*)(ws +  34 * MB);   // 16 MiB (dead after FFN1)
    __bf16* Hb    = (__bf16*)(ws +  51 * MB);   // 64 MiB
    __bf16* QKVb  = (__bf16*)(ws + 119 * MB);   //  6.3 MB [8192][384]
    __bf16* W1b   = (__bf16*)(ws + 126 * MB);   //  8.4 MB
    __bf16* W2b   = (__bf16*)(ws + 135 * MB);   //  8.4 MB
    __bf16* Wqkvb = (__bf16*)(ws + 144 * MB);   //  0.8 MB [384][1024]
    __bf16* Wpb   = (__bf16*)(ws + 145 * MB);   //  0.3 MB
    float*  Part  = (float*) (ws + 146 * MB);   //  4.2 MB
    __bf16* KtvTb = (__bf16*)(ws + 151 * MB);   //  32 KB
    __bf16* Ctxb  = (__bf16*)(ws + 152 * MB);   //  2.1 MB
    float*  bqkvf = (float*) (ws + 155 * MB);   //  1.5 KB

    const dim3 blk(256);

    // casts
    cast_f32_bf16<<<2048, blk, 0, stream>>>(x,  xb,           MROWS * DMODEL / 8);
    cast_f32_bf16<<<64,   blk, 0, stream>>>(Wq, Wqkvb,        DK * DMODEL / 8);
    cast_f32_bf16<<<64,   blk, 0, stream>>>(Wk, Wqkvb + DK * DMODEL,     DK * DMODEL / 8);
    cast_f32_bf16<<<64,   blk, 0, stream>>>(Wv, Wqkvb + 2 * DK * DMODEL, DK * DMODEL / 8);
    cast_f32_bf16<<<64,   blk, 0, stream>>>(Wp, Wpb,          DMODEL * DK / 8);
    cast_f32_bf16<<<1024, blk, 0, stream>>>(W1, W1b,          DFF * DMODEL / 8);
    cast_f32_bf16<<<1024, blk, 0, stream>>>(W2, W2b,          DMODEL * DFF / 8);
    pack_bias3<<<1, 128, 0, stream>>>(bq, bk, bv, bqkvf);

    // QKV packed projection -> bf16 [8192,384]
    gemm128<false,false,true,true,false><<<dim3(3, 64), blk, 0, stream>>>(
        xb, DMODEL, Wqkvb, bqkvf, nullptr, QKVb, nullptr, 3 * DK, DMODEL);

    // KtV (128x128) -> transposed bf16
    ktv_partial<<<64, blk, 0, stream>>>(QKVb + DK, QKVb + 2 * DK, 3 * DK, Part);
    ktv_reduce <<<64, blk, 0, stream>>>(Part, KtvTb);

    // context = Q @ KtV -> bf16 [8192,128]
    gemm128<false,false,false,true,false><<<dim3(1, 64), blk, 0, stream>>>(
        QKVb, 3 * DK, KtvTb, nullptr, nullptr, Ctxb, nullptr, DK, DK);

    // x2 = x + ctx @ Wp^T + bp -> fp32 d_out AND bf16 x2b (fused cast)
    gemm128<false,true,true,false,true><<<dim3(8, 64), blk, 0, stream>>>(
        Ctxb, DK, Wpb, bp, x, out, x2b, DMODEL, DK);

    // h = relu(x2 @ W1^T + b1) -> bf16 [8192,4096]; 512 blocks; nt=16
    gemm256p<true,false,true,true><<<512, 512, 0, stream>>>(
        x2b, DMODEL, W1b, DMODEL, b1, nullptr, Hb, 0, DFF,
        DMODEL, 512, DFF / 256);

    // FFN2 split-K=2 -> bf16 partials P0,P1; 256 blocks; nt=32
    gemm256p<false,false,false,true><<<256, 512, 0, stream>>>(
        Hb, DFF, W2b, DFF, nullptr, nullptr, P0,
        (long)MROWS * DMODEL, DMODEL, DFF / 2, 128, DMODEL / 256);

    // y = x2 + P0 + P1 + b2 (in-place on d_out)
    ffn2_reduce<<<2048, blk, 0, stream>>>(out, P0, P1, b2, MROWS * DMODEL / 8);
}

// Round 8
// 240.910 us; speedup vs baseline: 1.2685x; 1.2685x over previous
//
#include <hip/hip_runtime.h>

// LinearAttentionBlock bf16 MFMA. Attention reassociated: Q@(K'V).
// FFN GEMMs: 256x256/BK=64, round-6 stage-early schedule, but K-loop LDS
// reads are INLINE-ASM ds_read_b128 (opaque to hipcc's alias/waitcnt pass,
// so no hidden vmcnt drains against global_load_lds staging), with manual
// lgkmcnt(0) + sched_barrier(0) fences (rule 18). Epilogue transposes
// through a per-wave LDS slot -> coalesced bf16x8 stores.
// FFN2: split-K=2 (256 blocks) + fused reduce. Small GEMMs: m97 128x128.

#define MROWS 8192
#define DMODEL 1024
#define DK 128
#define DFF 4096

typedef __attribute__((ext_vector_type(8))) __bf16 bf16x8;
typedef __attribute__((ext_vector_type(4))) float f32x4;

#define BAR()    __builtin_amdgcn_s_barrier()
#define WAITV(n) asm volatile("s_waitcnt vmcnt(" #n ")" ::: "memory")
#define LGKM0()  asm volatile("s_waitcnt lgkmcnt(0)" ::: "memory")
#define SCHED0() __builtin_amdgcn_sched_barrier(0)
#define GLOAD(src, dst) __builtin_amdgcn_global_load_lds( \
    (const __attribute__((address_space(1))) void*)(src), \
    (__attribute__((address_space(3))) void*)(dst), 16, 0, 0)

// LDS byte offset of a generic pointer into __shared__
#define LDSO(p) ((unsigned)(unsigned long long) \
    (__attribute__((address_space(3))) const char*)(const char*)(p))

__device__ __forceinline__ bf16x8 ldsr(unsigned off) {
    bf16x8 r;
    asm volatile("ds_read_b128 %0, %1" : "=v"(r) : "v"(off));
    return r;
}

__global__ __launch_bounds__(256) void cast_f32_bf16(
    const float* __restrict__ src, __bf16* __restrict__ dst, int n8)
{
    for (int i = blockIdx.x * blockDim.x + threadIdx.x; i < n8;
         i += gridDim.x * blockDim.x) {
        const float4 a = reinterpret_cast<const float4*>(src)[2 * i];
        const float4 b = reinterpret_cast<const float4*>(src)[2 * i + 1];
        bf16x8 o;
        o[0] = (__bf16)a.x; o[1] = (__bf16)a.y; o[2] = (__bf16)a.z; o[3] = (__bf16)a.w;
        o[4] = (__bf16)b.x; o[5] = (__bf16)b.y; o[6] = (__bf16)b.z; o[7] = (__bf16)b.w;
        reinterpret_cast<bf16x8*>(dst)[i] = o;
    }
}

__device__ __forceinline__ void cast_one(const float* s, __bf16* d, int i) {
    const float4 a = reinterpret_cast<const float4*>(s)[2 * i];
    const float4 b = reinterpret_cast<const float4*>(s)[2 * i + 1];
    bf16x8 o;
    o[0] = (__bf16)a.x; o[1] = (__bf16)a.y; o[2] = (__bf16)a.z; o[3] = (__bf16)a.w;
    o[4] = (__bf16)b.x; o[5] = (__bf16)b.y; o[6] = (__bf16)b.z; o[7] = (__bf16)b.w;
    reinterpret_cast<bf16x8*>(d)[i] = o;
}

// all six weight casts in one launch. grid = 4*64 + 2*2048 = 4352 blocks.
__global__ __launch_bounds__(256) void cast6(
    const float* __restrict__ s0, __bf16* __restrict__ d0,
    const float* __restrict__ s1, __bf16* __restrict__ d1,
    const float* __restrict__ s2, __bf16* __restrict__ d2,
    const float* __restrict__ s3, __bf16* __restrict__ d3,
    const float* __restrict__ s4, __bf16* __restrict__ d4,
    const float* __restrict__ s5, __bf16* __restrict__ d5)
{
    const int b = blockIdx.x, t = threadIdx.x;
    if      (b <  64)  cast_one(s0, d0, b * 256 + t);
    else if (b < 128)  cast_one(s1, d1, (b - 64) * 256 + t);
    else if (b < 192)  cast_one(s2, d2, (b - 128) * 256 + t);
    else if (b < 256)  cast_one(s3, d3, (b - 192) * 256 + t);
    else if (b < 2304) cast_one(s4, d4, (b - 256) * 256 + t);
    else               cast_one(s5, d5, (b - 2304) * 256 + t);
}

__global__ void pack_bias3(const float* __restrict__ a, const float* __restrict__ b,
                           const float* __restrict__ c, float* __restrict__ o)
{
    const int t = threadIdx.x;
    o[t] = a[t]; o[128 + t] = b[t]; o[256 + t] = c[t];
}

// y = x2 + P0 + P1 + b2
__global__ __launch_bounds__(256) void ffn2_reduce(
    float* __restrict__ y, const __bf16* __restrict__ P0,
    const __bf16* __restrict__ P1, const float* __restrict__ b2, int n8)
{
    for (int i = blockIdx.x * blockDim.x + threadIdx.x; i < n8;
         i += gridDim.x * blockDim.x) {
        const int col0 = (i << 3) & (DMODEL - 1);
        const float4 ba = *reinterpret_cast<const float4*>(&b2[col0]);
        const float4 bb = *reinterpret_cast<const float4*>(&b2[col0 + 4]);
        float4 o0 = reinterpret_cast<const float4*>(y)[2 * i];
        float4 o1 = reinterpret_cast<const float4*>(y)[2 * i + 1];
        const bf16x8 p0 = reinterpret_cast<const bf16x8*>(P0)[i];
        const bf16x8 p1 = reinterpret_cast<const bf16x8*>(P1)[i];
        o0.x += (float)p0[0] + (float)p1[0] + ba.x;
        o0.y += (float)p0[1] + (float)p1[1] + ba.y;
        o0.z += (float)p0[2] + (float)p1[2] + ba.z;
        o0.w += (float)p0[3] + (float)p1[3] + ba.w;
        o1.x += (float)p0[4] + (float)p1[4] + bb.x;
        o1.y += (float)p0[5] + (float)p1[5] + bb.y;
        o1.z += (float)p0[6] + (float)p1[6] + bb.z;
        o1.w += (float)p0[7] + (float)p1[7] + bb.w;
        reinterpret_cast<float4*>(y)[2 * i]     = o0;
        reinterpret_cast<float4*>(y)[2 * i + 1] = o1;
    }
}

// ---------------------------------------------------------------------------
// 128x128 m97-style GEMM (round-2 proven). DUAL adds a bf16 secondary output.
// ---------------------------------------------------------------------------
template<bool RELU, bool RESID, bool BIAS, bool OUTBF, bool DUAL>
__global__ __launch_bounds__(256) void gemm128(
    const __bf16* __restrict__ A, int lda,
    const __bf16* __restrict__ W,
    const float* __restrict__ bias,
    const float* __restrict__ resid,
    void* __restrict__ Cout, __bf16* __restrict__ Cbf, int ldc, int K)
{
    constexpr int BK = 32;
    __shared__ __bf16 As[128 * BK];
    __shared__ __bf16 Bs[128 * BK];

    const int tid  = threadIdx.x;
    const int lane = tid & 63;
    const int w    = tid >> 6;
    const int wm   = w >> 1;
    const int wn   = w & 1;
    const int fr   = lane & 15;
    const int fq   = lane >> 4;

    const long row0 = (long)blockIdx.y * 128;
    const long col0 = (long)blockIdx.x * 128;

    const int sr = (w << 4) + (lane >> 2);
    const int sc = (lane & 3) << 3;

    const __bf16* gA0 = A + (row0 + sr) * (long)lda + sc;
    const __bf16* gA1 = A + (row0 + 64 + sr) * (long)lda + sc;
    const __bf16* gW0 = W + (col0 + sr) * (long)K + sc;
    const __bf16* gW1 = W + (col0 + 64 + sr) * (long)K + sc;

    __bf16* lA0 = &As[(w << 4) * BK];
    __bf16* lA1 = &As[((w << 4) + 64) * BK];
    __bf16* lB0 = &Bs[(w << 4) * BK];
    __bf16* lB1 = &Bs[((w << 4) + 64) * BK];

    f32x4 acc[4][4] = {};

    for (int k0 = 0; k0 < K; k0 += BK) {
        GLOAD(gA0 + k0, lA0);
        GLOAD(gA1 + k0, lA1);
        GLOAD(gW0 + k0, lB0);
        GLOAD(gW1 + k0, lB1);
        __syncthreads();

        bf16x8 af[4], bfr[4];
        #pragma unroll
        for (int m = 0; m < 4; m++)
            af[m] = *reinterpret_cast<const bf16x8*>(
                &As[(wm * 64 + m * 16 + fr) * BK + fq * 8]);
        #pragma unroll
        for (int n = 0; n < 4; n++)
            bfr[n] = *reinterpret_cast<const bf16x8*>(
                &Bs[(wn * 64 + n * 16 + fr) * BK + fq * 8]);

        #pragma unroll
        for (int m = 0; m < 4; m++)
            #pragma unroll
            for (int n = 0; n < 4; n++)
                acc[m][n] = __builtin_amdgcn_mfma_f32_16x16x32_bf16(
                    af[m], bfr[n], acc[m][n], 0, 0, 0);
        __syncthreads();
    }

    float bc[4];
    #pragma unroll
    for (int n = 0; n < 4; n++)
        bc[n] = BIAS ? bias[col0 + wn * 64 + n * 16 + fr] : 0.0f;
    #pragma unroll
    for (int m = 0; m < 4; m++) {
        #pragma unroll
        for (int j = 0; j < 4; j++) {
            const long r = row0 + wm * 64 + m * 16 + fq * 4 + j;
            #pragma unroll
            for (int n = 0; n < 4; n++) {
                const long c = col0 + wn * 64 + n * 16 + fr;
                float v = acc[m][n][j] + bc[n];
                if constexpr (RESID) v += resid[r * ldc + c];
                if constexpr (RELU)  v = fmaxf(v, 0.0f);
                if constexpr (OUTBF) ((__bf16*)Cout)[r * ldc + c] = (__bf16)v;
                else                 ((float*)Cout)[r * ldc + c] = v;
                if constexpr (DUAL)  Cbf[r * ldc + c] = (__bf16)v;
            }
        }
    }
}

// ---------------------------------------------------------------------------
// 256x256/BK=64, 512 thr = 8 waves (2M x 4N), per-wave 128x64, bf16 out only.
// LDS = 2 tile-slots x {B0,B1,A0,A1} x 16KB. Round-6 stage-early schedule:
//   ph0: asm-read B(8)+A m0-1(4); BAR; LGKM0+SCHED0; MFMA m0-1; BAR
//   ph1: asm-read A m2-5(8); stage(t+2,B0,B1); BAR; LGKM0+SCHED0; MFMA m2-3; BAR
//   ph2: asm-read A m6-7(4); BAR; SCHED0; MFMA m4-5; LGKM0; BAR
//   ph3: stage(t+2,A0,A1); SCHED0; MFMA m6-7; WAITV(8); BAR
// vmcnt ledger: prologue 16 issued, WAITV(8) retires tile0; steady 16 in
// flight, WAITV(8) retires tile t+1; tail WAITV(0) at t=nt-2.
// Epilogue: per-wave LDS transpose -> bf16x8 coalesced stores.
// ---------------------------------------------------------------------------
#define RD_B()                                             \
    _Pragma("unroll")                                      \
    for (int n = 0; n < 4; n++) {                          \
        bb[n][0] = ldsr(pB + rb0 + n * 2048);              \
        bb[n][1] = ldsr(pB + rb1 + n * 2048);              \
    }
#define RD_A(m0_, cnt_)                                    \
    _Pragma("unroll")                                      \
    for (int m = m0_; m < m0_ + cnt_; m++) {               \
        a[m][0] = ldsr(pA + rb0 + m * 2048);               \
        a[m][1] = ldsr(pA + rb1 + m * 2048);               \
    }
#define MFMA2(m0_)                                                            \
    _Pragma("unroll")                                                         \
    for (int m = m0_; m < m0_ + 2; m++)                                       \
        _Pragma("unroll")                                                     \
        for (int n = 0; n < 4; n++) {                                         \
            acc[m][n] = __builtin_amdgcn_mfma_f32_16x16x32_bf16(              \
                a[m][0], bb[n][0], acc[m][n], 0, 0, 0);                       \
            acc[m][n] = __builtin_amdgcn_mfma_f32_16x16x32_bf16(              \
                a[m][1], bb[n][1], acc[m][n], 0, 0, 0);                       \
        }

template<bool RELU, bool BIAS>
__global__ __launch_bounds__(512, 2) void gemm256p(
    const __bf16* __restrict__ A, int lda,
    const __bf16* __restrict__ W, int ldw,
    const float* __restrict__ bias,
    __bf16* __restrict__ Cout, long sstride, int ldc,
    int klen, int nb, int nbx)
{
    __shared__ char lds[8][16384];

    const int bid = blockIdx.x;
    const int sid = bid / nb;
    const int ib  = bid % nb;
    const int chunk = nb >> 3;
    const int swz   = (ib & 7) * chunk + (ib >> 3);
    const int bx    = swz % nbx;
    const int by    = swz / nbx;

    const long row0 = (long)by * 256;
    const long col0 = (long)bx * 256;

    const __bf16* Ash = A + (long)sid * klen;
    const __bf16* Wsh = W + (long)sid * klen;

    const int tid  = threadIdx.x;
    const int lane = tid & 63;
    const int w    = tid >> 6;
    const int wm   = w >> 2;
    const int wn   = w & 3;
    const int fr   = lane & 15;
    const int fq   = lane >> 4;

    const int srow8 = lane >> 3;
    const int scole = ((lane & 7) ^ srow8) << 3;    // T2 pre-swizzled col
    const __bf16* gA = Ash + (row0 + w * 8 + srow8) * (long)lda + scole;
    const __bf16* gB = Wsh + (col0 + w * 8 + srow8) * (long)ldw + scole;

    char* ldsc = &lds[0][0];
    const unsigned lbase = LDSO(ldsc);
    const int nt = klen >> 6;   // even, >= 2

    auto stage = [&](int u, int j) {
        if (u >= nt) return;
        char* dst = ldsc + (((u & 1) << 2 | j) << 14) + (w << 10);
        if (j < 2) {
            const __bf16* s = gB + ((long)j * 128) * (long)ldw + (long)u * 64;
            GLOAD(s, dst);
            GLOAD(s + 64 * (long)ldw, dst + 8192);
        } else {
            const __bf16* s = gA + ((long)(j - 2) * 128) * (long)lda + (long)u * 64;
            GLOAD(s, dst);
            GLOAD(s + 64 * (long)lda, dst + 8192);
        }
    };

    const unsigned rb0 = fr * 128 + ((fq * 16) ^ ((fr & 7) << 4));
    const unsigned rb1 = fr * 128 + ((64 + fq * 16) ^ ((fr & 7) << 4));

    f32x4 acc[8][4] = {};
    bf16x8 a[8][2], bb[4][2];

    // prologue
    stage(0, 0); stage(0, 1); stage(0, 2); stage(0, 3);
    stage(1, 0); stage(1, 1); stage(1, 2); stage(1, 3);
    WAITV(8);
    BAR();

    for (int t = 0; t < nt; ++t) {
        const unsigned base = lbase + ((t & 1) << 16);
        const unsigned pB = base + ((wn >> 1) << 14) + ((wn & 1) << 13);
        const unsigned pA = base + ((2 + wm) << 14);

        // ph0
        RD_B(); RD_A(0, 2);
        BAR();
        LGKM0(); SCHED0();
        __builtin_amdgcn_s_setprio(1); MFMA2(0); __builtin_amdgcn_s_setprio(0);
        BAR();
        // ph1
        RD_A(2, 4);
        stage(t + 2, 0); stage(t + 2, 1);
        BAR();
        LGKM0(); SCHED0();
        __builtin_amdgcn_s_setprio(1); MFMA2(2); __builtin_amdgcn_s_setprio(0);
        BAR();
        // ph2
        RD_A(6, 2);
        BAR();
        SCHED0();
        __builtin_amdgcn_s_setprio(1); MFMA2(4); __builtin_amdgcn_s_setprio(0);
        LGKM0();
        BAR();
        // ph3
        stage(t + 2, 2); stage(t + 2, 3);
        SCHED0();
        __builtin_amdgcn_s_setprio(1); MFMA2(6); __builtin_amdgcn_s_setprio(0);
        if (t + 2 < nt)      { WAITV(8); }
        else if (t + 1 < nt) { WAITV(0); }
        BAR();
    }

    // ---- epilogue: per-wave LDS transpose, coalesced bf16x8 stores
    __bf16* Cb = Cout + (long)sid * sstride;
    float bc[4];
    #pragma unroll
    for (int n = 0; n < 4; n++)
        bc[n] = BIAS ? bias[col0 + wn * 64 + n * 16 + fr] : 0.0f;

    __bf16* sw = reinterpret_cast<__bf16*>(ldsc) + (w << 13);  // 16KB slot
    #pragma unroll
    for (int m = 0; m < 8; m++)
        #pragma unroll
        for (int j = 0; j < 4; j++) {
            const int row = m * 16 + fq * 4 + j;
            #pragma unroll
            for (int n = 0; n < 4; n++) {
                float v = acc[m][n][j] + bc[n];
                if constexpr (RELU) v = fmaxf(v, 0.0f);
                sw[row * 64 + n * 16 + fr] = (__bf16)v;
            }
        }
    // same-wave RAW on private slot; compiler orders via lgkmcnt
    const long crow0 = row0 + wm * 128;
    const long ccol0 = col0 + wn * 64;
    #pragma unroll
    for (int i = 0; i < 16; i++) {
        const bf16x8 vv = *reinterpret_cast<const bf16x8*>(sw + i * 512 + lane * 8);
        const int r  = i * 8 + (lane >> 3);
        const int cg = (lane & 7) << 3;
        *reinterpret_cast<bf16x8*>(&Cb[(crow0 + r) * (long)ldc + ccol0 + cg]) = vv;
    }
}

// ---------------------------------------------------------------------------
// K^T @ V partials + reduce
// ---------------------------------------------------------------------------
__global__ __launch_bounds__(256) void ktv_partial(
    const __bf16* __restrict__ Kp, const __bf16* __restrict__ Vp,
    int ld, float* __restrict__ part)
{
    __shared__ float ks[32][DK];
    __shared__ float vs[32][DK];
    const int tid = threadIdx.x;
    const int ti  = tid >> 4;
    const int tj  = tid & 15;
    float acc[8][8] = {};
    const long base = (long)blockIdx.x * 128;

    for (int n0 = 0; n0 < 128; n0 += 32) {
        for (int t = tid; t < 512; t += 256) {
            const int r  = t >> 4;
            const int cc = (t & 15) << 3;
            const bf16x8 k8 = *reinterpret_cast<const bf16x8*>(
                &Kp[(base + n0 + r) * (long)ld + cc]);
            const bf16x8 v8 = *reinterpret_cast<const bf16x8*>(
                &Vp[(base + n0 + r) * (long)ld + cc]);
            #pragma unroll
            for (int u = 0; u < 8; u++) {
                ks[r][cc + u] = (float)k8[u];
                vs[r][cc + u] = (float)v8[u];
            }
        }
        __syncthreads();
        for (int n = 0; n < 32; n++) {
            float kk[8], vv[8];
            #pragma unroll
            for (int i = 0; i < 8; i++) kk[i] = ks[n][(ti << 3) + i];
            #pragma unroll
            for (int j = 0; j < 8; j++) vv[j] = vs[n][(tj << 3) + j];
            #pragma unroll
            for (int i = 0; i < 8; i++)
                #pragma unroll
                for (int j = 0; j < 8; j++)
                    acc[i][j] = fmaf(kk[i], vv[j], acc[i][j]);
        }
        __syncthreads();
    }

    float* dst = &part[(long)blockIdx.x * (DK * DK)];
    #pragma unroll
    for (int i = 0; i < 8; i++) {
        const int ig = (ti << 3) + i;
        *reinterpret_cast<float4*>(&dst[ig * DK + (tj << 3)]) =
            make_float4(acc[i][0], acc[i][1], acc[i][2], acc[i][3]);
        *reinterpret_cast<float4*>(&dst[ig * DK + (tj << 3) + 4]) =
            make_float4(acc[i][4], acc[i][5], acc[i][6], acc[i][7]);
    }
}

__global__ __launch_bounds__(256) void ktv_reduce(
    const float* __restrict__ part, __bf16* __restrict__ ktvT)
{
    const int t = blockIdx.x * 256 + threadIdx.x;
    const int i = t >> 7;
    const int j = t & 127;
    float s = 0.0f;
    for (int b = 0; b < 64; b++) s += part[(long)b * (DK * DK) + t];
    ktvT[j * DK + i] = (__bf16)s;
}

// ---------------------------------------------------------------------------
extern "C" void kernel_launch(void* const* d_in, const int* in_sizes, int n_in,
                              void* d_out, int out_size, void* d_ws, size_t ws_size,
                              hipStream_t stream) {
    const float* x  = (const float*)d_in[0];
    const float* Wq = (const float*)d_in[1];
    const float* bq = (const float*)d_in[2];
    const float* Wk = (const float*)d_in[3];
    const float* bk = (const float*)d_in[4];
    const float* Wv = (const float*)d_in[5];
    const float* bv = (const float*)d_in[6];
    const float* Wp = (const float*)d_in[7];
    const float* bp = (const float*)d_in[8];
    const float* W1 = (const float*)d_in[9];
    const float* b1 = (const float*)d_in[10];
    const float* W2 = (const float*)d_in[11];
    const float* b2 = (const float*)d_in[12];
    float* out = (float*)d_out;

    char* ws = (char*)d_ws;
    const size_t MB = 1ull << 20;
    __bf16* xb    = (__bf16*)(ws);              // 16 MiB (dead after QKV)
    __bf16* P0    = (__bf16*)(ws);              // shard-0 partial
    __bf16* P1    = P0 + (long)MROWS * DMODEL;  // shard-1 partial (ws+16MiB)
    __bf16* x2b   = (__bf16*)(ws +  34 * MB);   // 16 MiB (dead after FFN1)
    __bf16* Hb    = (__bf16*)(ws +  51 * MB);   // 64 MiB
    __bf16* QKVb  = (__bf16*)(ws + 119 * MB);   //  6.3 MB [8192][384]
    __bf16* W1b   = (__bf16*)(ws + 126 * MB);   //  8.4 MB
    __bf16* W2b   = (__bf16*)(ws + 135 * MB);   //  8.4 MB
    __bf16* Wqkvb = (__bf16*)(ws + 144 * MB);   //  0.8 MB [384][1024]
    __bf16* Wpb   = (__bf16*)(ws + 145 * MB);   //  0.3 MB
    float*  Part  = (float*) (ws + 146 * MB);   //  4.2 MB
    __bf16* KtvTb = (__bf16*)(ws + 151 * MB);   //  32 KB
    __bf16* Ctxb  = (__bf16*)(ws + 152 * MB);   //  2.1 MB
    float*  bqkvf = (float*) (ws + 155 * MB);   //  1.5 KB

    const dim3 blk(256);

    // casts: x (separate) + all weights (one launch)
    cast_f32_bf16<<<2048, blk, 0, stream>>>(x, xb, MROWS * DMODEL / 8);
    cast6<<<4352, blk, 0, stream>>>(
        Wq, Wqkvb, Wk, Wqkvb + DK * DMODEL, Wv, Wqkvb + 2 * DK * DMODEL,
        Wp, Wpb, W1, W1b, W2, W2b);
    pack_bias3<<<1, 128, 0, stream>>>(bq, bk, bv, bqkvf);

    // QKV packed projection -> bf16 [8192,384]
    gemm128<false,false,true,true,false><<<dim3(3, 64), blk, 0, stream>>>(
        xb, DMODEL, Wqkvb, bqkvf, nullptr, QKVb, nullptr, 3 * DK, DMODEL);

    // KtV (128x128) -> transposed bf16
    ktv_partial<<<64, blk, 0, stream>>>(QKVb + DK, QKVb + 2 * DK, 3 * DK, Part);
    ktv_reduce <<<64, blk, 0, stream>>>(Part, KtvTb);

    // context = Q @ KtV -> bf16 [8192,128]
    gemm128<false,false,false,true,false><<<dim3(1, 64), blk, 0, stream>>>(
        QKVb, 3 * DK, KtvTb, nullptr, nullptr, Ctxb, nullptr, DK, DK);

    // x2 = x + ctx @ Wp^T + bp -> fp32 d_out AND bf16 x2b (fused cast)
    gemm128<false,true,true,false,true><<<dim3(8, 64), blk, 0, stream>>>(
        Ctxb, DK, Wpb, bp, x, out, x2b, DMODEL, DK);

    // h = relu(x2 @ W1^T + b1) -> bf16 [8192,4096]; 512 blocks; nt=16
    gemm256p<true,true><<<512, 512, 0, stream>>>(
        x2b, DMODEL, W1b, DMODEL, b1, Hb, 0, DFF, DMODEL, 512, DFF / 256);

    // FFN2 split-K=2 -> bf16 partials P0,P1; 256 blocks; nt=32
    gemm256p<false,false><<<256, 512, 0, stream>>>(
        Hb, DFF, W2b, DFF, nullptr, P0,
        (long)MROWS * DMODEL, DMODEL, DFF / 2, 128, DMODEL / 256);

    // y = x2 + P0 + P1 + b2 (in-place on d_out)
    ffn2_reduce<<<2048, blk, 0, stream>>>(out, P0, P1, b2, MROWS * DMODEL / 8);
}